// Round 8
// baseline (1104.082 us; speedup 1.0000x reference)
//
#include <hip/hip_runtime.h>

// Fused MS-SSIM + L1, single pass. B=128, H=W=384 fp32.
// Levels k=1,2,4,7, box conv, zero pad p=k/2 (even k -> 385x385 output).
// Round 8: packed-fp32 (x,y) pipelines + tail-free residency.
//  - All per-column quantities processed as float2: (x,y) and (x2,y2) use
//    v_pk_add/mul_f32 (gfx90a+ packed math), xy cross-term scalar.
//  - Pipeline (validated r7): raw loads -> 6-slot ring (gap 2) ->
//    bpermute (masked input) -> A/B sets (gap 1) -> compute.
//  - BAND=64 x 6 bands, 128-thread (2-wave) blocks: 2688 blocks,
//    21 waves/CU needed <= 24 resident at VGPR<=85 -> single round.

#define W 384
#define H 384
#define NB 128
#define BAND 64
#define NTILES 7
#define NBLK (NTILES * 3 * NB)   // grid (7,3,128) = 2688 blocks

typedef float f2 __attribute__((ext_vector_type(2)));

__device__ __forceinline__ float bp(int addr, float v) {
    return __int_as_float(__builtin_amdgcn_ds_bpermute(addr, __float_as_int(v)));
}

// S for box window k*k from UNNORMALIZED sums {Sx,Sy,Sxx,Syy,Sxy}.
// k2 = k^2, c1k4 = C1*k^4, c2k4 = C2*k^4 (1/k^2 factors cancel).
__device__ __forceinline__ float ssim_u(float Sx, float Sy, float Sxx, float Syy,
                                        float Sxy, float k2, float c1k4, float c2k4) {
    const float p  = Sx * Sy;
    float sq = Sx * Sx;
    sq = fmaf(Sy, Sy, sq);
    const float A1 = fmaf(2.f, p, c1k4);
    const float t  = fmaf(k2, Sxy, -p);
    const float A2 = fmaf(2.f, t, c2k4);
    const float B1 = sq + c1k4;
    const float sw = Sxx + Syy;
    const float B2 = fmaf(k2, sw, -sq) + c2k4;
    return (A1 * A2) * __builtin_amdgcn_rcpf(B1 * B2);
}

__global__ __launch_bounds__(128, 6) void msssim_main(
    const float* __restrict__ X, const float* __restrict__ Y,
    const float* __restrict__ dr, float* __restrict__ part)
{
    const int lane = threadIdx.x & 63;
    const int wv   = threadIdx.x >> 6;          // 0..1
    const int tile = blockIdx.x;                // 0..6
    const int band = blockIdx.y * 2 + wv;       // 0..5
    const int b    = blockIdx.z;

    const int cbase = -3 + 56 * tile;           // window-start col of lane 0
    const int c     = cbase + lane;             // this lane's column
    const int R0    = BAND * band;

    // per-level output-row bounds (wave-uniform):
    // k1,k7: 384 rows; k2,k4: 385 rows (band 5 takes the extra row)
    const int g1hi  = R0 + BAND;                      // k1,k7: [R0, R0+64)
    const int g24hi = (band == 5) ? 385 : R0 + BAND;  // k2,k4: [R0, g24hi)

    const float drb = dr[b];
    const float C1 = (0.01f * drb) * (0.01f * drb);
    const float C2 = (0.03f * drb) * (0.03f * drb);
    const float C1_2 = C1 * 16.f,   C2_2 = C2 * 16.f;     // k=2
    const float C1_4 = C1 * 256.f,  C2_4 = C2 * 256.f;    // k=4
    const float C1_7 = C1 * 2401.f, C2_7 = C2 * 2401.f;   // k=7

    // ownership masks (validated rounds 2-7): output col j = c + k/2
    const float m1 = (lane >= 3 && lane <= 58 && c     <= 383) ? 1.f : 0.f;
    const float m2 = (lane >= 2 && lane <= 57 && c + 1 <= 384) ? 1.f : 0.f;
    const float m4 = (lane >= 1 && lane <= 56 && c + 2 <= 384) ? 1.f : 0.f;
    const float m7 = (             lane <= 55 && c + 3 <= 383) ? 1.f : 0.f;

    // own-column load setup (clamped offset + zero mask, row-invariant)
    const float mcol = (c >= 0 && c < W) ? 1.f : 0.f;
    const f2    mcol2 = { mcol, mcol };
    const int   cc   = c < 0 ? 0 : (c > W - 1 ? W - 1 : c);

    // bpermute byte addresses for shifts d=1..6 (hw wraps mod 64; wrapped
    // lanes produce garbage that the ownership masks exclude)
    int ad[6];
#pragma unroll
    for (int d = 1; d <= 6; ++d) ad[d - 1] = ((lane + d) & 63) << 2;

    const float* __restrict__ Xb = X + (size_t)b * (H * W);
    const float* __restrict__ Yb = Y + (size_t)b * (H * W);

    // vertical ring buffers of horizontal window sums:
    // *xy = packed (Sx,Sy), *q = packed (Sxx,Syy), *s = scalar Sxy
    f2 r2xy, r2q; float r2s;
    f2 r4xy[3], r4q[3]; float r4s[3];
    f2 r7xy[6], r7q[6]; float r7s[6];
    r2xy = (f2){0.f, 0.f}; r2q = (f2){0.f, 0.f}; r2s = 0.f;
#pragma unroll
    for (int a = 0; a < 3; ++a) { r4xy[a] = (f2){0.f,0.f}; r4q[a] = (f2){0.f,0.f}; r4s[a] = 0.f; }
#pragma unroll
    for (int a = 0; a < 6; ++a) { r7xy[a] = (f2){0.f,0.f}; r7q[a] = (f2){0.f,0.f}; r7s[a] = 0.f; }

    float ss1 = 0.f;
    f2 a24 = {0.f, 0.f};   // (ss2, ss4)
    f2 a7l = {0.f, 0.f};   // (ss7, l1)

    const int u0 = R0 - 3;   // 72 steps: u in [R0-3, R0+68] (needed: R0+66)

    // 6-slot raw-value ring (RAW loads only -> vmcnt sinks to first use)
    f2 pv[6];
    auto loadv = [&](int u, f2& v) {
        if (u >= 0 && u < H) {               // wave-uniform branch
            v.x = Xb[(size_t)u * W + cc];
            v.y = Yb[(size_t)u * W + cc];
        } else { v = (f2){0.f, 0.f}; }
    };

    // A/B shifted-value sets: filled at step t-1, consumed at step t.
    // Boundary mask applied to the bpermute INPUT (per-source-column).
    f2 Aset[7], Bset[7];
    auto do_bperm = [&](f2 raw, f2* s) {
        const f2 v = raw * mcol2;
        s[0] = v;
#pragma unroll
        for (int d = 1; d <= 6; ++d) {
            s[d].x = bp(ad[d - 1], v.x);
            s[d].y = bp(ad[d - 1], v.y);
        }
    };

    // prologue: preload rows u0..u0+2; A = shifts of row u0
    loadv(u0,     pv[0]);
    loadv(u0 + 1, pv[1]);
    loadv(u0 + 2, pv[2]);
    do_bperm(pv[0], Aset);

    for (int s = 0; s < 72; s += 6) {
#pragma unroll
        for (int ph = 0; ph < 6; ++ph) {
            const int u = u0 + s + ph;       // compute row

            // stage 1: load row u+3 into slot (ph+3)%6 (gap 2 to bperm)
            loadv(u + 3, pv[(ph + 3) % 6]);

            // stage 2: bpermute row u+1 (loaded 2 steps ago)
            // stage 3: compute row u from the set filled last step
            const bool evenT = ((ph & 1) == 0);
            f2* nset = evenT ? Bset : Aset;
            const f2* xa = evenT ? Aset : Bset;
            do_bperm(pv[(ph + 1) % 6], nset);

            // products (packed squares + scalar cross)
            f2 q[7]; float sx[7];
#pragma unroll
            for (int i = 0; i < 7; ++i) {
                q[i]  = xa[i] * xa[i];
                sx[i] = xa[i].x * xa[i].y;
            }

            // hierarchical horizontal sums
            const f2 w2xy = xa[0] + xa[1];
            const f2 w4xy = w2xy + (xa[2] + xa[3]);
            const f2 w7xy = w4xy + ((xa[4] + xa[5]) + xa[6]);
            const f2 w2q  = q[0] + q[1];
            const f2 w4q  = w2q + (q[2] + q[3]);
            const f2 w7q  = w4q + ((q[4] + q[5]) + q[6]);
            const float w2s = sx[0] + sx[1];
            const float w4s = w2s + (sx[2] + sx[3]);
            const float w7s = w4s + ((sx[4] + sx[5]) + sx[6]);

            // vertical window sums
            const f2 V2xy = w2xy + r2xy;
            const f2 V2q  = w2q  + r2q;
            const float V2s = w2s + r2s;
            const f2 V4xy = w4xy + (r4xy[0] + r4xy[1] + r4xy[2]);
            const f2 V4q  = w4q  + (r4q[0]  + r4q[1]  + r4q[2]);
            const float V4s = w4s + (r4s[0] + r4s[1] + r4s[2]);
            const f2 V7xy = w7xy + ((r7xy[0] + r7xy[1]) + (r7xy[2] + r7xy[3]) + (r7xy[4] + r7xy[5]));
            const f2 V7q  = w7q  + ((r7q[0]  + r7q[1])  + (r7q[2]  + r7q[3])  + (r7q[4]  + r7q[5]));
            const float V7s = w7s + ((r7s[0] + r7s[1]) + (r7s[2] + r7s[3]) + (r7s[4] + r7s[5]));

            // ring shifts
            r2xy = w2xy; r2q = w2q; r2s = w2s;
            r4xy[2] = r4xy[1]; r4xy[1] = r4xy[0]; r4xy[0] = w4xy;
            r4q[2]  = r4q[1];  r4q[1]  = r4q[0];  r4q[0]  = w4q;
            r4s[2]  = r4s[1];  r4s[1]  = r4s[0];  r4s[0]  = w4s;
#pragma unroll
            for (int a = 5; a > 0; --a) { r7xy[a] = r7xy[a-1]; r7q[a] = r7q[a-1]; r7s[a] = r7s[a-1]; }
            r7xy[0] = w7xy; r7q[0] = w7q; r7s[0] = w7s;

            // k=1 (closed form), output row i=u, col j=c
            if (u >= R0 && u < g1hi) {
                const float xv = xa[0].x, yv = xa[0].y;
                const float s1 = fmaf(2.f, xv * yv, C1) *
                                 __builtin_amdgcn_rcpf(fmaf(xv, xv, fmaf(yv, yv, C1)));
                ss1 = fmaf(s1, m1, ss1);
            }
            // k=2, i=u
            if (u >= R0 && u < g24hi) {
                const float s2 = ssim_u(V2xy.x, V2xy.y, V2q.x, V2q.y, V2s, 4.f, C1_2, C2_2);
                a24.x = fmaf(s2, m2, a24.x);
            }
            // k=4, i=u-1
            {
                const int i = u - 1;
                if (i >= R0 && i < g24hi) {
                    const float s4 = ssim_u(V4xy.x, V4xy.y, V4q.x, V4q.y, V4s, 16.f, C1_4, C2_4);
                    a24.y = fmaf(s4, m4, a24.y);
                }
            }
            // k=7, i=u-3, plus L1 (|Sx-Sy|, 1/49 applied in reduce)
            {
                const int i = u - 3;
                if (i >= R0 && i < g1hi) {
                    const float s7 = ssim_u(V7xy.x, V7xy.y, V7q.x, V7q.y, V7s, 49.f, C1_7, C2_7);
                    const f2 v7 = { s7, fabsf(V7xy.x - V7xy.y) };
                    const f2 mm = { m7, m7 };
                    a7l += v7 * mm;
                }
            }
        }
    }

    // wave reduce -> block reduce -> one float store per block per quantity
    float ss2 = a24.x, ss4 = a24.y, ss7 = a7l.x, l1 = a7l.y;
#pragma unroll
    for (int d = 32; d > 0; d >>= 1) {
        ss1 += __shfl_down(ss1, d, 64);
        ss2 += __shfl_down(ss2, d, 64);
        ss4 += __shfl_down(ss4, d, 64);
        ss7 += __shfl_down(ss7, d, 64);
        l1  += __shfl_down(l1,  d, 64);
    }
    __shared__ float sred[2][5];
    if (lane == 0) {
        sred[wv][0] = ss1; sred[wv][1] = ss2; sred[wv][2] = ss4;
        sred[wv][3] = ss7; sred[wv][4] = l1;
    }
    __syncthreads();
    if (threadIdx.x == 0) {
        const int bid = ((int)blockIdx.z * 3 + (int)blockIdx.y) * NTILES + (int)blockIdx.x;
#pragma unroll
        for (int q = 0; q < 5; ++q)
            part[bid * 5 + q] = sred[0][q] + sred[1][q];
    }
}

__global__ __launch_bounds__(256) void reduce_final(
    const float* __restrict__ part, float* __restrict__ out)
{
    const int lane = threadIdx.x & 63;
    const int wv   = threadIdx.x >> 6;
    double d[5] = {0, 0, 0, 0, 0};
    for (int i = threadIdx.x; i < NBLK; i += 256) {
#pragma unroll
        for (int q = 0; q < 5; ++q) d[q] += (double)part[i * 5 + q];
    }
#pragma unroll
    for (int s = 32; s > 0; s >>= 1) {
#pragma unroll
        for (int q = 0; q < 5; ++q) d[q] += __shfl_down(d[q], s, 64);
    }
    __shared__ double sd[4][5];
    if (lane == 0) {
#pragma unroll
        for (int q = 0; q < 5; ++q) sd[wv][q] = d[q];
    }
    __syncthreads();
    if (threadIdx.x == 0) {
        double a[5];
#pragma unroll
        for (int q = 0; q < 5; ++q)
            a[q] = sd[0][q] + sd[1][q] + sd[2][q] + sd[3][q];
        const double n384 = (double)NB * 384.0 * 384.0;
        const double n385 = (double)NB * 385.0 * 385.0;
        const double m  = (a[0] / n384) * (a[1] / n385) * (a[2] / n385) * (a[3] / n384);
        const double l1 = a[4] / 49.0 / n384;
        out[0] = (float)(0.84 * (1.0 - m) + 0.16 * l1);
    }
}

extern "C" void kernel_launch(void* const* d_in, const int* in_sizes, int n_in,
                              void* d_out, int out_size, void* d_ws, size_t ws_size,
                              hipStream_t stream) {
    const float* X  = (const float*)d_in[0];
    const float* Y  = (const float*)d_in[1];
    const float* dr = (const float*)d_in[2];
    float* out  = (float*)d_out;
    float* part = (float*)d_ws;   // NBLK*5 floats = 53.8 KB

    dim3 grid(NTILES, 3, NB);
    msssim_main<<<grid, 128, 0, stream>>>(X, Y, dr, part);
    reduce_final<<<1, 256, 0, stream>>>(part, out);
}

// Round 9
// 243.169 us; speedup vs baseline: 4.5404x; 4.5404x over previous
//
#include <hip/hip_runtime.h>

// Fused MS-SSIM + L1, single pass. B=128, H=W=384 fp32.
// Levels k=1,2,4,7, box conv, zero pad p=k/2 (even k -> 385x385 output).
// Round 9: r7 inner loop (validated, scalar register arrays only) with
// single-round residency geometry:
//   - 192-thread (3-wave) blocks, BAND=64, 6 bands, grid (7,2,128)
//   - 1792 blocks x 3 waves = 21 waves/CU, all resident at VGPR<=85
//     -> no straggler round (r7 ran 6+1 blocks/CU = 2 rounds).
// Pipeline: raw loads -> 6-slot scalar ring (gap 2, vmcnt sinks to use)
// -> bpermute (masked input) -> A/B scalar sets (gap 1) -> compute.

#define W 384
#define H 384
#define NB 128
#define BAND 64
#define NTILES 7
#define NBLK (NTILES * 2 * NB)   // grid (7,2,128) = 1792 blocks

__device__ __forceinline__ float bp(int addr, float v) {
    return __int_as_float(__builtin_amdgcn_ds_bpermute(addr, __float_as_int(v)));
}

// S for box window k*k from UNNORMALIZED sums V = {Sx,Sy,Sxx,Syy,Sxy}.
// k2 = k^2, c1k4 = C1*k^4, c2k4 = C2*k^4 (1/k^2 factors cancel).
__device__ __forceinline__ float ssim_u(const float* V, float k2, float c1k4, float c2k4) {
    const float Sx = V[0], Sy = V[1], Sxx = V[2], Syy = V[3], Sxy = V[4];
    const float p  = Sx * Sy;
    float sq = Sx * Sx;
    sq = fmaf(Sy, Sy, sq);
    const float A1 = fmaf(2.f, p, c1k4);
    const float t  = fmaf(k2, Sxy, -p);
    const float A2 = fmaf(2.f, t, c2k4);
    const float B1 = sq + c1k4;
    const float sw = Sxx + Syy;
    const float B2 = fmaf(k2, sw, -sq) + c2k4;
    return (A1 * A2) * __builtin_amdgcn_rcpf(B1 * B2);
}

__global__ __launch_bounds__(192) void msssim_main(
    const float* __restrict__ X, const float* __restrict__ Y,
    const float* __restrict__ dr, float* __restrict__ part)
{
    const int lane = threadIdx.x & 63;
    const int wv   = threadIdx.x >> 6;          // 0..2
    const int tile = blockIdx.x;                // 0..6
    const int band = blockIdx.y * 3 + wv;       // 0..5
    const int b    = blockIdx.z;

    const int cbase = -3 + 56 * tile;           // window-start col of lane 0
    const int c     = cbase + lane;             // this lane's column
    const int R0    = BAND * band;

    // per-level output-row bounds (wave-uniform):
    // k1,k7: 384 rows; k2,k4: 385 rows (band 5 takes the extra row)
    const int g1hi  = R0 + BAND;                      // k1,k7: [R0, R0+64)
    const int g24hi = (band == 5) ? 385 : R0 + BAND;  // k2,k4: [R0, g24hi)

    const float drb = dr[b];
    const float C1 = (0.01f * drb) * (0.01f * drb);
    const float C2 = (0.03f * drb) * (0.03f * drb);
    const float C1_2 = C1 * 16.f,   C2_2 = C2 * 16.f;     // k=2
    const float C1_4 = C1 * 256.f,  C2_4 = C2 * 256.f;    // k=4
    const float C1_7 = C1 * 2401.f, C2_7 = C2 * 2401.f;   // k=7

    // ownership masks (validated rounds 2-7): output col j = c + k/2
    const float m1 = (lane >= 3 && lane <= 58 && c     <= 383) ? 1.f : 0.f;
    const float m2 = (lane >= 2 && lane <= 57 && c + 1 <= 384) ? 1.f : 0.f;
    const float m4 = (lane >= 1 && lane <= 56 && c + 2 <= 384) ? 1.f : 0.f;
    const float m7 = (             lane <= 55 && c + 3 <= 383) ? 1.f : 0.f;

    // own-column load setup (clamped offset + zero mask, row-invariant)
    const float mcol = (c >= 0 && c < W) ? 1.f : 0.f;
    const int   cc   = c < 0 ? 0 : (c > W - 1 ? W - 1 : c);

    // bpermute byte addresses for shifts d=1..6 (hw wraps mod 64; wrapped
    // lanes produce garbage that the ownership masks exclude)
    int ad[6];
#pragma unroll
    for (int d = 1; d <= 6; ++d) ad[d - 1] = ((lane + d) & 63) << 2;

    const float* __restrict__ Xb = X + (size_t)b * (H * W);
    const float* __restrict__ Yb = Y + (size_t)b * (H * W);

    // vertical ring buffers of horizontal window sums (per quantity)
    float r2[5], r4[3][5], r7[6][5];
#pragma unroll
    for (int q = 0; q < 5; ++q) {
        r2[q] = 0.f;
        r4[0][q] = r4[1][q] = r4[2][q] = 0.f;
#pragma unroll
        for (int a = 0; a < 6; ++a) r7[a][q] = 0.f;
    }

    float ss1 = 0.f, ss2 = 0.f, ss4 = 0.f, ss7 = 0.f, l1 = 0.f;

    const int u0 = R0 - 3;   // 72 steps: u in [R0-3, R0+68] (needed: R0+66)

    // 6-slot raw-value ring: RAW loads only so the vmcnt wait sinks to use.
    float px[6], py[6];
    auto loadv = [&](int u, float& x, float& y) {
        if (u >= 0 && u < H) {               // wave-uniform branch
            x = Xb[(size_t)u * W + cc];
            y = Yb[(size_t)u * W + cc];
        } else { x = 0.f; y = 0.f; }
    };

    // A/B shifted-value sets: set filled at step t-1, consumed at step t.
    // Boundary mask applied to the bpermute INPUT (per-source-column).
    float Ax[7], Ay[7], Bx[7], By[7];
    auto do_bperm = [&](float xr, float yr, float* sx, float* sy) {
        const float xv = xr * mcol;
        const float yv = yr * mcol;
        sx[0] = xv; sy[0] = yv;
#pragma unroll
        for (int d = 1; d <= 6; ++d) {
            sx[d] = bp(ad[d - 1], xv);
            sy[d] = bp(ad[d - 1], yv);
        }
    };

    // prologue: preload rows u0..u0+2; A = shifts of row u0
    loadv(u0,     px[0], py[0]);
    loadv(u0 + 1, px[1], py[1]);
    loadv(u0 + 2, px[2], py[2]);
    do_bperm(px[0], py[0], Ax, Ay);

    for (int s = 0; s < 72; s += 6) {
#pragma unroll
        for (int ph = 0; ph < 6; ++ph) {
            const int u = u0 + s + ph;       // compute row

            // stage 1: load row u+3 into slot (ph+3)%6  (gap 2 to bperm)
            loadv(u + 3, px[(ph + 3) % 6], py[(ph + 3) % 6]);

            // stage 2: bpermute row u+1 (slot (ph+1)%6, loaded 2 steps ago)
            // stage 3: compute row u from the set filled last step
            const bool evenT = ((ph & 1) == 0);
            float* nx = evenT ? Bx : Ax;
            float* ny = evenT ? By : Ay;
            const float* xa = evenT ? Ax : Bx;
            const float* ya = evenT ? Ay : By;
            do_bperm(px[(ph + 1) % 6], py[(ph + 1) % 6], nx, ny);

            float V2[5], V4[5], V7[5];
#pragma unroll
            for (int q = 0; q < 5; ++q) {
                float e[7];
#pragma unroll
                for (int i = 0; i < 7; ++i) {
                    e[i] = (q == 0) ? xa[i]
                         : (q == 1) ? ya[i]
                         : (q == 2) ? xa[i] * xa[i]
                         : (q == 3) ? ya[i] * ya[i]
                         :            xa[i] * ya[i];
                }
                const float w2 = e[0] + e[1];
                const float w4 = w2 + (e[2] + e[3]);
                const float w7 = w4 + ((e[4] + e[5]) + e[6]);
                V2[q] = w2 + r2[q];
                V4[q] = w4 + (r4[0][q] + r4[1][q] + r4[2][q]);
                V7[q] = w7 + ((r7[0][q] + r7[1][q]) + (r7[2][q] + r7[3][q])
                              + (r7[4][q] + r7[5][q]));
                r2[q] = w2;
                r4[2][q] = r4[1][q]; r4[1][q] = r4[0][q]; r4[0][q] = w4;
                r7[5][q] = r7[4][q]; r7[4][q] = r7[3][q]; r7[3][q] = r7[2][q];
                r7[2][q] = r7[1][q]; r7[1][q] = r7[0][q]; r7[0][q] = w7;
            }

            // k=1 (closed form), output row i=u, col j=c
            if (u >= R0 && u < g1hi) {
                const float xv = xa[0], yv = ya[0];
                const float s1 = fmaf(2.f, xv * yv, C1) *
                                 __builtin_amdgcn_rcpf(fmaf(xv, xv, fmaf(yv, yv, C1)));
                ss1 = fmaf(s1, m1, ss1);
            }
            // k=2, i=u
            if (u >= R0 && u < g24hi) {
                ss2 = fmaf(ssim_u(V2, 4.f, C1_2, C2_2), m2, ss2);
            }
            // k=4, i=u-1
            {
                const int i = u - 1;
                if (i >= R0 && i < g24hi) {
                    ss4 = fmaf(ssim_u(V4, 16.f, C1_4, C2_4), m4, ss4);
                }
            }
            // k=7, i=u-3, plus L1 (|Sx-Sy|, 1/49 applied in reduce)
            {
                const int i = u - 3;
                if (i >= R0 && i < g1hi) {
                    ss7 = fmaf(ssim_u(V7, 49.f, C1_7, C2_7), m7, ss7);
                    l1  = fmaf(fabsf(V7[0] - V7[1]), m7, l1);
                }
            }
        }
    }

    // wave reduce -> block reduce -> one float store per block per quantity
#pragma unroll
    for (int d = 32; d > 0; d >>= 1) {
        ss1 += __shfl_down(ss1, d, 64);
        ss2 += __shfl_down(ss2, d, 64);
        ss4 += __shfl_down(ss4, d, 64);
        ss7 += __shfl_down(ss7, d, 64);
        l1  += __shfl_down(l1,  d, 64);
    }
    __shared__ float sred[3][5];
    if (lane == 0) {
        sred[wv][0] = ss1; sred[wv][1] = ss2; sred[wv][2] = ss4;
        sred[wv][3] = ss7; sred[wv][4] = l1;
    }
    __syncthreads();
    if (threadIdx.x == 0) {
        const int bid = ((int)blockIdx.z * 2 + (int)blockIdx.y) * NTILES + (int)blockIdx.x;
#pragma unroll
        for (int q = 0; q < 5; ++q)
            part[bid * 5 + q] = sred[0][q] + sred[1][q] + sred[2][q];
    }
}

__global__ __launch_bounds__(256) void reduce_final(
    const float* __restrict__ part, float* __restrict__ out)
{
    const int lane = threadIdx.x & 63;
    const int wv   = threadIdx.x >> 6;
    double d[5] = {0, 0, 0, 0, 0};
    for (int i = threadIdx.x; i < NBLK; i += 256) {
#pragma unroll
        for (int q = 0; q < 5; ++q) d[q] += (double)part[i * 5 + q];
    }
#pragma unroll
    for (int s = 32; s > 0; s >>= 1) {
#pragma unroll
        for (int q = 0; q < 5; ++q) d[q] += __shfl_down(d[q], s, 64);
    }
    __shared__ double sd[4][5];
    if (lane == 0) {
#pragma unroll
        for (int q = 0; q < 5; ++q) sd[wv][q] = d[q];
    }
    __syncthreads();
    if (threadIdx.x == 0) {
        double a[5];
#pragma unroll
        for (int q = 0; q < 5; ++q)
            a[q] = sd[0][q] + sd[1][q] + sd[2][q] + sd[3][q];
        const double n384 = (double)NB * 384.0 * 384.0;
        const double n385 = (double)NB * 385.0 * 385.0;
        const double m  = (a[0] / n384) * (a[1] / n385) * (a[2] / n385) * (a[3] / n384);
        const double l1 = a[4] / 49.0 / n384;
        out[0] = (float)(0.84 * (1.0 - m) + 0.16 * l1);
    }
}

extern "C" void kernel_launch(void* const* d_in, const int* in_sizes, int n_in,
                              void* d_out, int out_size, void* d_ws, size_t ws_size,
                              hipStream_t stream) {
    const float* X  = (const float*)d_in[0];
    const float* Y  = (const float*)d_in[1];
    const float* dr = (const float*)d_in[2];
    float* out  = (float*)d_out;
    float* part = (float*)d_ws;   // NBLK*5 floats = 35.8 KB

    dim3 grid(NTILES, 2, NB);
    msssim_main<<<grid, 192, 0, stream>>>(X, Y, dr, part);
    reduce_final<<<1, 256, 0, stream>>>(part, out);
}